// Round 7
// baseline (241.607 us; speedup 1.0000x reference)
//
#include <hip/hip_runtime.h>

// Non-local (SAGAN) block on MI355X. B=8, C=256, C'=64, N=4096.
// Round 7: flash = 32x32 MFMA (half the LDS-frag reads/FLOP) + NSPL=2 + split
// MFMA chains (fixes round-4's latency collapse); qkv = coalesced float4 x-read
// via LDS bf16 transpose tile (replaces 64 stride-4096 scalar loads/thread).
// ws: qT 4MB | kT 4MB | vB 4MB | Op[2][b][n][c'] f32 16MB | Lg[2][b][n] 256KB | Wb 128KB

#define Bsz 8
#define Cch 256
#define CPd 64
#define Nn  4096
#define TIL 64
#define NSPL 2
#define MHALF (Nn / NSPL)

typedef __attribute__((ext_vector_type(8)))  short short8;   // 8 bf16 (MFMA A/B frag)
typedef __attribute__((ext_vector_type(4)))  float f32x4;    // 16x16 C/D frag
typedef __attribute__((ext_vector_type(16))) float f32x16;   // 32x32 C/D frag

static constexpr float C1 = (float)(1.41421 / 16.0);  // ROOT_2/sqrt(C)
static constexpr float C2 = (float)(1.41421 / 8.0);   // ROOT_2/sqrt(C')

__device__ inline unsigned pk_trunc(float lo, float hi) { // -> bf16x2 (truncate), 1 v_perm
    return __builtin_amdgcn_perm(__float_as_uint(hi), __float_as_uint(lo), 0x07060302u);
}
__device__ inline float dpp_swap1(float v) {  // lane l <-> l^1 (quad_perm [1,0,3,2])
    return __uint_as_float((unsigned)__builtin_amdgcn_mov_dpp(
        (int)__float_as_uint(v), 0xB1, 0xF, 0xF, true));
}

// -------------------------------------------------------- W f32->bf16 conv --
__global__ __launch_bounds__(256) void wconv_kernel(
    const float* __restrict__ Wq, const float* __restrict__ Wk,
    const float* __restrict__ Wv, const float* __restrict__ Wo,
    unsigned short* __restrict__ Wb)
{
    const int idx = (blockIdx.x * 256 + threadIdx.x) * 4;
    const float* src = (idx < 16384) ? Wq : (idx < 32768) ? Wk : (idx < 49152) ? Wv : Wo;
    const float4 v = *(const float4*)(src + (idx & 16383));
    *(uint2*)(Wb + idx) = make_uint2(pk_trunc(v.x, v.y), pk_trunc(v.z, v.w));
}

// --------------------------------------------------------- QKV proj (MFMA) --
// Round 7: x staged via coalesced float4 -> LDS bf16 [n][c] (stride 132 uints,
// writes 2-way/free); A-frags hoisted once; LDS tile then reused as T.
__global__ __launch_bounds__(256) void qkv_kernel(
    const float* __restrict__ x, const unsigned short* __restrict__ Wb,
    const float* __restrict__ bq, const float* __restrict__ bk, const float* __restrict__ bv,
    unsigned short* __restrict__ qT, unsigned short* __restrict__ kT,
    unsigned short* __restrict__ vB)
{
    __shared__ __align__(16) unsigned XsT[TIL * 132];         // 33.8 KB: x bf16 [n][c]; later T f32
    __shared__ __align__(16) unsigned short Wlds[CPd * 264];  // 33 KB

    const int b   = blockIdx.y;
    const int n0  = blockIdx.x * TIL;
    const int t   = threadIdx.x;
    const int g   = t >> 6;
    const int l15 = t & 15;
    const int l4  = (t & 63) >> 4;

    {   // stage x [c=256][n=64] f32 -> XsT[n][c-pair] bf16x2, coalesced reads
        const float* xb = x + (size_t)b * Cch * Nn + n0;
        const int tc = t & 15;       // c'-group
        const int tn = t >> 4;       // n-group (0..15)
        #pragma unroll
        for (int cc = 0; cc < 8; ++cc) {
            const int cp = tc + 16 * cc;                 // c' = c/2, 0..127
            const float4 f0 = *(const float4*)(xb + (size_t)(2 * cp + 0) * Nn + 4 * tn);
            const float4 f1 = *(const float4*)(xb + (size_t)(2 * cp + 1) * Nn + 4 * tn);
            XsT[(4 * tn + 0) * 132 + cp] = pk_trunc(C1 * f0.x, C1 * f1.x);
            XsT[(4 * tn + 1) * 132 + cp] = pk_trunc(C1 * f0.y, C1 * f1.y);
            XsT[(4 * tn + 2) * 132 + cp] = pk_trunc(C1 * f0.z, C1 * f1.z);
            XsT[(4 * tn + 3) * 132 + cp] = pk_trunc(C1 * f0.w, C1 * f1.w);
        }
    }
    __syncthreads();

    // hoist A-frags: lane row n = 16g+l15, k = c = 8*l4 + j + 32*ks
    short8 xf[8];
    {
        const unsigned short* xrow = (const unsigned short*)&XsT[(16 * g + l15) * 132];
        #pragma unroll
        for (int ks = 0; ks < 8; ++ks) xf[ks] = *(const short8*)(xrow + 8 * l4 + 32 * ks);
    }
    __syncthreads();   // XsT reads done; space becomes T

    float* T = (float*)XsT;   // [64][68] f32, 17.4 KB (fits in XsT)

    #pragma unroll
    for (int mat = 0; mat < 3; ++mat) {
        {   // stage W[64][256] bf16, coalesced
            const uint4* wg = (const uint4*)(Wb + mat * 16384);
            #pragma unroll
            for (int p = 0; p < 8; ++p) {
                const int idx = p * 256 + t;
                const int o = idx >> 5, cs = idx & 31;
                *(uint4*)&Wlds[o * 264 + cs * 8] = wg[idx];
            }
        }
        __syncthreads();

        const float* bias = (mat == 0) ? bq : (mat == 1) ? bk : bv;
        f32x4 acc[4];
        #pragma unroll
        for (int st = 0; st < 4; ++st) {
            const float bb = bias[16 * st + l15];
            acc[st] = (f32x4){bb, bb, bb, bb};
        }
        #pragma unroll
        for (int st = 0; st < 4; ++st) {
            #pragma unroll
            for (int ks = 0; ks < 8; ++ks) {
                const short8 wf = *(const short8*)&Wlds[(16 * st + l15) * 264 + 8 * l4 + 32 * ks];
                acc[st] = __builtin_amdgcn_mfma_f32_16x16x32_bf16(xf[ks], wf, acc[st], 0, 0, 0);
            }
        }
        __syncthreads();   // Wlds reads + prev T reads done

        if (mat < 2) {     // T as [n][c']
            #pragma unroll
            for (int st = 0; st < 4; ++st)
                #pragma unroll
                for (int r = 0; r < 4; ++r)
                    T[(16 * g + 4 * l4 + r) * 68 + 16 * st + l15] = acc[st][r];
        } else {           // v: T as [c'][n]
            #pragma unroll
            for (int st = 0; st < 4; ++st)
                #pragma unroll
                for (int r = 0; r < 4; ++r)
                    T[(16 * st + l15) * 68 + 16 * g + 4 * l4 + r] = acc[st][r];
        }
        __syncthreads();

        const int row = t >> 2;            // n (q/k) or c' (v)
        const int sg  = 16 * (t & 3);
        const float4 a0 = *(const float4*)&T[row * 68 + sg + 0];
        const float4 a1 = *(const float4*)&T[row * 68 + sg + 4];
        const float4 a2 = *(const float4*)&T[row * 68 + sg + 8];
        const float4 a3 = *(const float4*)&T[row * 68 + sg + 12];
        const uint4 lo = make_uint4(pk_trunc(a0.x, a0.y), pk_trunc(a0.z, a0.w),
                                    pk_trunc(a1.x, a1.y), pk_trunc(a1.z, a1.w));
        const uint4 hi = make_uint4(pk_trunc(a2.x, a2.y), pk_trunc(a2.z, a2.w),
                                    pk_trunc(a3.x, a3.y), pk_trunc(a3.z, a3.w));
        unsigned short* dst;
        if (mat < 2) {
            dst = (mat == 0 ? qT : kT) + ((size_t)(b * Nn + n0 + row)) * CPd + sg;
        } else {
            dst = vB + ((size_t)(b * CPd + row)) * Nn + n0 + sg;
        }
        *(uint4*)dst = lo;
        *(uint4*)(dst + 8) = hi;
        __syncthreads();   // T reads done before next mat's T writes
    }
}

// ------------------------------------------------------ flash (32x32 MFMA) --
// Round-4 tiling (layout HW-verified there) + NSPL=2 + split MFMA chains.
// Waves: nh = w&1 (n half), mq = w>>1 (m half / c half).
__global__ __launch_bounds__(256, 4) void flash_kernel(
    const unsigned short* __restrict__ qT, const unsigned short* __restrict__ kT,
    const unsigned short* __restrict__ vB, float* __restrict__ Op, float* __restrict__ Lg)
{
    __shared__ __align__(16) unsigned short Ks[TIL * 72];  // [m][c]
    __shared__ __align__(16) unsigned short Vs[TIL * 72];  // [c][m]
    __shared__ __align__(16) unsigned Pb[TIL * 40];        // bf16-pair [n][m/2], stride 40 u32
    __shared__ float Lsh[TIL];

    const int b   = blockIdx.y;
    const int n0  = blockIdx.x * TIL;
    const int s   = blockIdx.z;
    const int t   = threadIdx.x;
    const int l   = t & 63;
    const int w   = t >> 6;
    const int nh  = w & 1;
    const int mq  = w >> 1;
    const int l31 = l & 31;
    const int l1  = l >> 5;

    if (t < TIL) Lsh[t] = 0.f;

    // Q A-frags from global: row n = n0+32nh+l31, kc: c = 16kc + 8*l1 + j
    short8 qf[4];
    {
        const unsigned short* qp = qT + (size_t)(b * Nn + n0 + 32 * nh + l31) * CPd + 8 * l1;
        #pragma unroll
        for (int kc = 0; kc < 4; ++kc) qf[kc] = *(const short8*)(qp + 16 * kc);
    }

    f32x16 acco_a, acco_b;
    float Lp[16];
    #pragma unroll
    for (int r = 0; r < 16; ++r) { acco_a[r] = 0.f; acco_b[r] = 0.f; Lp[r] = 0.f; }

    const uint4* kg = (const uint4*)(kT + (size_t)b * Nn * CPd);
    const unsigned short* vb = vB + (size_t)b * CPd * Nn;
    const unsigned sel = (l & 1) ? 0x03020706u : 0x07060302u;
    const int par  = l & 1;
    const int colp = 16 * mq + (l31 >> 1);
    const int mbase = s * MHALF;

    for (int mi = 0; mi < MHALF; mi += TIL) {
        const int m0 = mbase + mi;
        __syncthreads();
        {   // stage K [m][c] and V [c][m]
            const int r = t >> 3, cc = t & 7;
            uint4 k0 = kg[(m0 + r) * 8 + cc];
            uint4 k1 = kg[(m0 + r + 32) * 8 + cc];
            *(uint4*)&Ks[r * 72 + 8 * cc]        = k0;
            *(uint4*)&Ks[(r + 32) * 72 + 8 * cc] = k1;
            uint4 w0 = *(const uint4*)(vb + (size_t)r * Nn + m0 + 8 * cc);
            uint4 w1 = *(const uint4*)(vb + (size_t)(r + 32) * Nn + m0 + 8 * cc);
            *(uint4*)&Vs[r * 72 + 8 * cc]        = w0;
            *(uint4*)&Vs[(r + 32) * 72 + 8 * cc] = w1;
        }
        __syncthreads();

        // ---- S subtile [32n x 32m]: two independent 2-MFMA chains ----
        f32x16 sa, sb;
        #pragma unroll
        for (int r = 0; r < 16; ++r) { sa[r] = 0.f; sb[r] = 0.f; }
        {
            const short8 kf0 = *(const short8*)&Ks[(32 * mq + l31) * 72 + 8 * l1];
            const short8 kf1 = *(const short8*)&Ks[(32 * mq + l31) * 72 + 16 + 8 * l1];
            const short8 kf2 = *(const short8*)&Ks[(32 * mq + l31) * 72 + 32 + 8 * l1];
            const short8 kf3 = *(const short8*)&Ks[(32 * mq + l31) * 72 + 48 + 8 * l1];
            sa = __builtin_amdgcn_mfma_f32_32x32x16_bf16(qf[0], kf0, sa, 0, 0, 0);
            sb = __builtin_amdgcn_mfma_f32_32x32x16_bf16(qf[1], kf1, sb, 0, 0, 0);
            sa = __builtin_amdgcn_mfma_f32_32x32x16_bf16(qf[2], kf2, sa, 0, 0, 0);
            sb = __builtin_amdgcn_mfma_f32_32x32x16_bf16(qf[3], kf3, sb, 0, 0, 0);
        }

        // ---- P = exp(S); DPP pair-pack; parity-split write ----
        unsigned u[16];
        #pragma unroll
        for (int r = 0; r < 16; ++r) {
            float p = __expf(sa[r] + sb[r]);
            Lp[r] += p;
            float nb = dpp_swap1(p);
            u[r] = __builtin_amdgcn_perm(__float_as_uint(nb), __float_as_uint(p), sel);
        }
        {
            const int rb = 32 * nh + 4 * l1 + 2 * par;
            #pragma unroll
            for (int q = 0; q < 4; ++q) {
                Pb[(rb + 8 * q) * 40 + colp]     = u[4 * q + 2 * par];
                Pb[(rb + 8 * q + 1) * 40 + colp] = u[4 * q + 2 * par + 1];
            }
        }
        __syncthreads();

        // ---- O subtile [32n x 32c] += P V^T: two persistent chains ----
        {
            const short8 pf0 = *(const short8*)&Pb[(32 * nh + l31) * 40 + 4 * l1];
            const short8 vf0 = *(const short8*)&Vs[(32 * mq + l31) * 72 + 8 * l1];
            acco_a = __builtin_amdgcn_mfma_f32_32x32x16_bf16(pf0, vf0, acco_a, 0, 0, 0);
            const short8 pf1 = *(const short8*)&Pb[(32 * nh + l31) * 40 + 8 + 4 * l1];
            const short8 vf1 = *(const short8*)&Vs[(32 * mq + l31) * 72 + 16 + 8 * l1];
            acco_b = __builtin_amdgcn_mfma_f32_32x32x16_bf16(pf1, vf1, acco_b, 0, 0, 0);
            const short8 pf2 = *(const short8*)&Pb[(32 * nh + l31) * 40 + 16 + 4 * l1];
            const short8 vf2 = *(const short8*)&Vs[(32 * mq + l31) * 72 + 32 + 8 * l1];
            acco_a = __builtin_amdgcn_mfma_f32_32x32x16_bf16(pf2, vf2, acco_a, 0, 0, 0);
            const short8 pf3 = *(const short8*)&Pb[(32 * nh + l31) * 40 + 24 + 4 * l1];
            const short8 vf3 = *(const short8*)&Vs[(32 * mq + l31) * 72 + 48 + 8 * l1];
            acco_b = __builtin_amdgcn_mfma_f32_32x32x16_bf16(pf3, vf3, acco_b, 0, 0, 0);
        }
    }

    // partial row-sums (once per block)
    #pragma unroll
    for (int r = 0; r < 16; ++r)
        atomicAdd(&Lsh[32 * nh + (r & 3) + 8 * (r >> 2) + 4 * l1], Lp[r]);
    __syncthreads();

    float* ob = Op + ((size_t)(s * Bsz + b) * Nn + n0) * CPd;
    #pragma unroll
    for (int r = 0; r < 16; ++r) {
        const int nl = 32 * nh + (r & 3) + 8 * (r >> 2) + 4 * l1;
        ob[(size_t)nl * CPd + 32 * mq + l31] = acco_a[r] + acco_b[r];
    }
    if (t < TIL) Lg[(size_t)(s * Bsz + b) * Nn + n0 + t] = Lsh[t];
}

// ------------------------------------------------------- output proj (MFMA) --
// (round-6 version: 512 threads, combines KV-split partials during staging)
__global__ __launch_bounds__(512) void out_kernel(
    const float* __restrict__ Op, const float* __restrict__ Lg,
    const unsigned short* __restrict__ Wob,
    const float* __restrict__ bo, const float* __restrict__ gamma,
    const float* __restrict__ x, float* __restrict__ y)
{
    __shared__ __align__(16) unsigned short Wos[Cch * 72];
    __shared__ __align__(16) unsigned short Sas[TIL * 72];
    __shared__ float bos[Cch];

    const int b   = blockIdx.y;
    const int n0  = blockIdx.x * TIL;
    const int t   = threadIdx.x;     // 0..511
    const int l   = t & 63;
    const int w   = t >> 6;
    const int l15 = l & 15;
    const int l4  = l >> 4;

    if (t < Cch) bos[t] = bo[t];
    {
        const uint4* wg = (const uint4*)Wob;
        #pragma unroll
        for (int p = 0; p < 4; ++p) {
            const int idx = p * 512 + t;
            const int row = idx >> 3, seg = idx & 7;
            *(uint4*)&Wos[row * 72 + seg * 8] = wg[idx];
        }
    }
    if (t < 256) {
        const int n = t >> 2, seg = t & 3;
        const float* o0 = Op + ((size_t)(b * Nn + n0 + n)) * CPd + seg * 16;
        const float* o1 = o0 + (size_t)Bsz * Nn * CPd;
        const float l0 = Lg[(size_t)b * Nn + n0 + n];
        const float l1 = Lg[(size_t)(Bsz + b) * Nn + n0 + n];
        const float sc = C2 / (l0 + l1);
        unsigned pk[8];
        #pragma unroll
        for (int i = 0; i < 4; ++i) {
            const float4 a = ((const float4*)o0)[i];
            const float4 c = ((const float4*)o1)[i];
            pk[2 * i]     = pk_trunc((a.x + c.x) * sc, (a.y + c.y) * sc);
            pk[2 * i + 1] = pk_trunc((a.z + c.z) * sc, (a.w + c.w) * sc);
        }
        *(uint4*)&Sas[n * 72 + seg * 16]     = make_uint4(pk[0], pk[1], pk[2], pk[3]);
        *(uint4*)&Sas[n * 72 + seg * 16 + 8] = make_uint4(pk[4], pk[5], pk[6], pk[7]);
    }
    __syncthreads();

    short8 bfr[4][2];
    #pragma unroll
    for (int ns = 0; ns < 4; ++ns) {
        bfr[ns][0] = *(const short8*)&Sas[(16 * ns + l15) * 72 + 8 * l4];
        bfr[ns][1] = *(const short8*)&Sas[(16 * ns + l15) * 72 + 8 * l4 + 32];
    }
    const float gam = gamma[0];
    const float* xb = x + (size_t)b * Cch * Nn;
    float*       yb = y + (size_t)b * Cch * Nn;

    #pragma unroll
    for (int os2 = 0; os2 < 2; ++os2) {
        const int obase = 16 * (w + 8 * os2);
        const short8 af0 = *(const short8*)&Wos[(obase + l15) * 72 + 8 * l4];
        const short8 af1 = *(const short8*)&Wos[(obase + l15) * 72 + 8 * l4 + 32];
        #pragma unroll
        for (int ns = 0; ns < 4; ++ns) {
            f32x4 acc = (f32x4){0.f, 0.f, 0.f, 0.f};
            acc = __builtin_amdgcn_mfma_f32_16x16x32_bf16(af0, bfr[ns][0], acc, 0, 0, 0);
            acc = __builtin_amdgcn_mfma_f32_16x16x32_bf16(af1, bfr[ns][1], acc, 0, 0, 0);
            #pragma unroll
            for (int r = 0; r < 4; ++r) {
                const int o = obase + 4 * l4 + r;
                const size_t idx = (size_t)o * Nn + n0 + 16 * ns + l15;
                yb[idx] = fmaf(gam, acc[r] + bos[o], xb[idx]);
            }
        }
    }
}

// ---------------------------------------------------------------------------
extern "C" void kernel_launch(void* const* d_in, const int* in_sizes, int n_in,
                              void* d_out, int out_size, void* d_ws, size_t ws_size,
                              hipStream_t stream)
{
    (void)in_sizes; (void)n_in; (void)out_size; (void)ws_size;
    const float* x     = (const float*)d_in[0];
    const float* Wq    = (const float*)d_in[1];
    const float* bq    = (const float*)d_in[2];
    const float* Wk    = (const float*)d_in[3];
    const float* bk    = (const float*)d_in[4];
    const float* Wv    = (const float*)d_in[5];
    const float* bv    = (const float*)d_in[6];
    const float* Wo    = (const float*)d_in[7];
    const float* bo    = (const float*)d_in[8];
    const float* gamma = (const float*)d_in[9];
    float* y = (float*)d_out;

    const size_t per = (size_t)Bsz * Nn * CPd;           // 2,097,152 elements
    unsigned short* qT = (unsigned short*)d_ws;          // 4 MB
    unsigned short* kT = qT + per;                       // 4 MB
    unsigned short* vB = kT + per;                       // 4 MB
    float* Op = (float*)(vB + per);                      // 16 MB
    float* Lg = Op + NSPL * per;                         // 256 KB
    unsigned short* Wb = (unsigned short*)(Lg + NSPL * Bsz * Nn);  // 128 KB

    dim3 grid(Nn / TIL, Bsz);
    dim3 gridF(Nn / TIL, Bsz, NSPL);
    wconv_kernel<<<64, 256, 0, stream>>>(Wq, Wk, Wv, Wo, Wb);
    qkv_kernel<<<grid, 256, 0, stream>>>(x, Wb, bq, bk, bv, qT, kT, vB);
    flash_kernel<<<gridF, 256, 0, stream>>>(qT, kT, vB, Op, Lg);
    out_kernel<<<grid, 512, 0, stream>>>(Op, Lg, Wb + 3 * 16384, bo, gamma, x, y);
}